// Round 7
// baseline (1139.339 us; speedup 1.0000x reference)
//
#include <hip/hip_runtime.h>

// ResidualVQ: B=8, T=2048, D=256, Q=8, K=1024. N = B*T = 16384.
// Scoring via fp16 split-MFMA: 2x = xh + xl, e = eh + el (fp16 RTNE).
// 2x.e ~= xh.eh + xh.el + xl.eh  (dropped xl.el ~ 2e-6, below fp32 noise).
// One GEMM, reduce length 768, mapped into 512-wide packed buffers:
//   d' in [0,512):   A: ecat col d' (eh|el)    B: xcat col (d' < 256 ? d' : d'-256)
//   d' in [512,768): A: ecat col d'-512 (eh)   B: xcat col d'-256 (xl)
// score = acc - |e|^2  (row-constant |x|^2 dropped; same argmax).
//
// ROUND 7: single persistent kernel. Grid 512 x 512thr, exactly 2 blocks/CU
// (LDS 77KB <= 80KB, launch_bounds(512,4) caps VGPR at 128 -> co-residency
// guaranteed). Block (slice, tokt) owns token tile tokt (128 rows) x code
// slice (256 codes). Only the 4 blocks of one tokt communicate; they sync
// via a device-scope atomic counter (RMW arrive + RMW poll, __threadfence
// release/acquire) -- correct regardless of XCD placement (G16), fast
// because the heuristic b&7 mapping puts all 4 on one XCD. Groups proceed
// through layers independently. build_xcat/update/finalize fused in.
//
// d_out (float): [0, N*D) quantized_out; [N*D,+Q*N) indices; [+Q) losses
// d_ws: xcat f16[N][512] | ecat f16[Q*K][512] | norms f32[Q*K]
//       | partial float2[4][N] | ctr u32[128]

typedef _Float16 f16;
typedef f16 f16x8 __attribute__((ext_vector_type(8)));
typedef float f32x4 __attribute__((ext_vector_type(4)));

constexpr int Dd = 256;
constexpr int Kk = 1024;
constexpr int Qq = 8;
constexpr int Nn = 16384;

__device__ inline void gload16(const f16* g, f16* l) {
    __builtin_amdgcn_global_load_lds(
        (const __attribute__((address_space(1))) unsigned int*)(const __attribute__((address_space(1))) f16*)g,
        (__attribute__((address_space(3))) unsigned int*)(__attribute__((address_space(3))) f16*)l,
        16, 0, 0);
}

// ---- build ecat[Q*K][512] = [eh|el] + squared norms, from fp32 codebooks ----
__global__ __launch_bounds__(256) void build_ecat(const float* __restrict__ cb,
                                                  f16* __restrict__ ecat,
                                                  float* __restrict__ norms) {
    int row = blockIdx.x * 8 + (threadIdx.x >> 5);
    int p = threadIdx.x & 31;
    const float* s = cb + (size_t)row * Dd + p * 8;
    f16x8 hi, lo;
    float sq = 0.f;
#pragma unroll
    for (int j = 0; j < 8; ++j) {
        float v = s[j];
        f16 h = (f16)v;
        hi[j] = h; lo[j] = (f16)(v - (float)h);
        sq = fmaf(v, v, sq);
    }
    *(f16x8*)(ecat + (size_t)row * 512 + p * 8) = hi;
    *(f16x8*)(ecat + (size_t)row * 512 + 256 + p * 8) = lo;
#pragma unroll
    for (int off = 16; off >= 1; off >>= 1) sq += __shfl_down(sq, off, 32);
    if (p == 0) norms[row] = sq;
}

// ---- 4-block group barrier (device-scope, coherent-point RMW both sides) ----
__device__ inline void group_sync(unsigned* ctr, unsigned target) {
    __syncthreads();
    if (threadIdx.x == 0) {
        __threadfence();   // release: push my global stores to coherent point
        __hip_atomic_fetch_add(ctr, 1u, __ATOMIC_RELEASE, __HIP_MEMORY_SCOPE_AGENT);
        while (__hip_atomic_fetch_add(ctr, 0u, __ATOMIC_RELAXED, __HIP_MEMORY_SCOPE_AGENT) < target)
            __builtin_amdgcn_s_sleep(2);
        __threadfence();   // acquire: invalidate caches before reading peers' data
    }
    __syncthreads();
}

// ---- the whole RVQ layer loop, one launch ----
__global__ __launch_bounds__(512, 4) void rvq_mega(
    const float* __restrict__ x,         // [N][256] fp32
    const float* __restrict__ cbs,       // [Q][K][256] fp32
    const f16* __restrict__ ecat_all,    // [Q*K][512]
    const float* __restrict__ norms_all, // [Q*K]
    f16* __restrict__ xcat,              // [N][512]
    float2* __restrict__ partial,        // [4][N]
    float* __restrict__ outq,            // d_out [N][256]
    float* __restrict__ idxs,            // d_out [Q][N]
    float* __restrict__ losses,          // d_out [Q]
    unsigned* __restrict__ ctr)          // [128], zeroed per launch
{
    __shared__ f16 tA[3][256 * 32];   // 48 KB
    __shared__ f16 tB[3][128 * 32];   // 24 KB
    __shared__ float smn[256];
    __shared__ float2 smg[4][128];
    __shared__ float lred[8];

    const int tid = threadIdx.x;
    const int w = tid >> 6, l = tid & 63;
    const int wr = w >> 1, wc = w & 1;          // wr: code quad, wc: token half
    const int l16 = l & 15, hi4 = l >> 4;

    const int b = blockIdx.x;
    const int slice = (b >> 3) & 3;             // 256-code slice
    const int tokt = ((b >> 5) << 3) | (b & 7); // token tile; 4 slice-blocks share b&7
    const int tbase = tokt * 128;
    const int qcb = slice * 256;
    unsigned* myctr = ctr + tokt;
    unsigned ep = 0;

    // update/build mapping: my 32 rows, 16 threads/row, 16 dims/thread
    const int ulr = tid >> 4;                   // 0..31
    const int up  = tid & 15;                   // 0..15
    const int urow = tbase + slice * 32 + ulr;

    // ---- pre-phase: build xcat (2x split) for my 32 rows ----
    {
        const float* xs = x + (size_t)urow * Dd + up * 16;
        f16* xr = xcat + (size_t)urow * 512 + up * 16;
#pragma unroll
        for (int c = 0; c < 2; ++c) {
            f16x8 hi, lo;
#pragma unroll
            for (int j = 0; j < 8; ++j) {
                float v = 2.f * xs[c * 8 + j];
                f16 h = (f16)v;
                hi[j] = h; lo[j] = (f16)(v - (float)h);
            }
            *(f16x8*)(xr + c * 8) = hi;
            *(f16x8*)(xr + 256 + c * 8) = lo;
        }
    }
    group_sync(myctr, 4 * (++ep));

    // score staging addresses (swizzled global source, linear LDS dest)
    const int srow = tid >> 2;
    const int scol = (((tid & 3) ^ ((tid >> 3) & 3))) * 8;
    const f16* gb = xcat + (size_t)(tbase + srow) * 512 + scol;

    // ds_read offsets with the same involution
    int offA[4], offB[4];
#pragma unroll
    for (int m = 0; m < 4; ++m) {
        int row = wr * 64 + m * 16 + l16;
        offA[m] = row * 32 + ((hi4 ^ ((row >> 1) & 3)) * 8);
    }
#pragma unroll
    for (int n = 0; n < 4; ++n) {
        int row = wc * 64 + n * 16 + l16;
        offB[n] = row * 32 + ((hi4 ^ ((row >> 1) & 3)) * 8);
    }

    for (int q = 0; q < Qq; ++q) {
        // ================= score phase =================
        const f16* ga = ecat_all + ((size_t)q * Kk + qcb + srow) * 512 + scol;
        if (tid < 256) smn[tid] = norms_all[q * Kk + qcb + tid];

        f32x4 acc[4][4];
#pragma unroll
        for (int m = 0; m < 4; ++m)
#pragma unroll
            for (int n = 0; n < 4; ++n) acc[m][n] = (f32x4){0.f, 0.f, 0.f, 0.f};

#define STAGE(NB, SS) do { \
        int d0 = (SS) * 32; \
        int aoff = d0 < 512 ? d0 : d0 - 512; \
        int boff = d0 < 256 ? d0 : d0 - 256; \
        gload16(ga + aoff,             &tA[NB][tid * 8]); \
        gload16(ga + aoff + 128 * 512, &tA[NB][4096 + tid * 8]); \
        gload16(gb + boff,             &tB[NB][tid * 8]); \
    } while (0)

#define COMPUTE(CB) do { \
        f16x8 af[4], bf[4]; \
        _Pragma("unroll") for (int m = 0; m < 4; ++m) af[m] = *(const f16x8*)&tA[CB][offA[m]]; \
        _Pragma("unroll") for (int n = 0; n < 4; ++n) bf[n] = *(const f16x8*)&tB[CB][offB[n]]; \
        _Pragma("unroll") for (int m = 0; m < 4; ++m) \
        _Pragma("unroll") for (int n = 0; n < 4; ++n) \
            acc[m][n] = __builtin_amdgcn_mfma_f32_16x16x32_f16(af[m], bf[n], acc[m][n], 0, 0, 0); \
    } while (0)

        STAGE(0, 0);
        STAGE(1, 1);
        asm volatile("s_waitcnt vmcnt(3)\n\ts_barrier" ::: "memory");

        for (int u = 0; u < 21; u += 3) {
            STAGE(2, u + 2); COMPUTE(0);
            asm volatile("s_waitcnt vmcnt(3) lgkmcnt(0)\n\ts_barrier" ::: "memory");
            STAGE(0, u + 3); COMPUTE(1);
            asm volatile("s_waitcnt vmcnt(3) lgkmcnt(0)\n\ts_barrier" ::: "memory");
            STAGE(1, u + 4); COMPUTE(2);
            asm volatile("s_waitcnt vmcnt(3) lgkmcnt(0)\n\ts_barrier" ::: "memory");
        }
        STAGE(2, 23); COMPUTE(0);
        asm volatile("s_waitcnt vmcnt(3) lgkmcnt(0)\n\ts_barrier" ::: "memory");
        COMPUTE(1);
        asm volatile("s_waitcnt vmcnt(0) lgkmcnt(0)\n\ts_barrier" ::: "memory");
        COMPUTE(2);
#undef STAGE
#undef COMPUTE

        // epilogue: score = acc - |e|^2 ; top-1 (ascending code order)
        float bv[4]; int bi[4];
#pragma unroll
        for (int n = 0; n < 4; ++n) { bv[n] = -3.4e38f; bi[n] = 0; }
#pragma unroll
        for (int m = 0; m < 4; ++m) {
#pragma unroll
            for (int r = 0; r < 4; ++r) {
                int cl = wr * 64 + m * 16 + hi4 * 4 + r;
                float nrm = smn[cl];
                int cg = qcb + cl;
#pragma unroll
                for (int n = 0; n < 4; ++n) {
                    float v = acc[m][n][r] - nrm;
                    if (v > bv[n]) { bv[n] = v; bi[n] = cg; }
                }
            }
        }
#pragma unroll
        for (int off = 16; off <= 32; off <<= 1) {
#pragma unroll
            for (int n = 0; n < 4; ++n) {
                float ov = __shfl_xor(bv[n], off);
                int oi = __shfl_xor(bi[n], off);
                if (ov > bv[n] || (ov == bv[n] && oi < bi[n])) { bv[n] = ov; bi[n] = oi; }
            }
        }
        if (l < 16) {
#pragma unroll
            for (int n = 0; n < 4; ++n)
                smg[wr][wc * 64 + n * 16 + l] = make_float2(bv[n], (float)bi[n]);
        }
        __syncthreads();
        if (tid < 128) {
            float2 r = smg[0][tid];
#pragma unroll
            for (int ww = 1; ww < 4; ++ww) {
                float2 c = smg[ww][tid];
                if (c.x > r.x || (c.x == r.x && c.y < r.y)) r = c;
            }
            partial[(size_t)slice * Nn + tbase + tid] = r;
        }
        group_sync(myctr, 4 * (++ep));

        // ================= update phase: my 32 rows =================
        float2 bsel = partial[urow];
#pragma unroll
        for (int qq = 1; qq < 4; ++qq) {
            float2 c = partial[(size_t)qq * Nn + urow];
            if (c.x > bsel.x || (c.x == bsel.x && c.y < bsel.y)) bsel = c;
        }
        const int k = (int)bsel.y;
        const float* cbrow = cbs + ((size_t)q * Kk + k) * Dd + up * 16;

        float rn[16];
        float lp = 0.f;
        if (q == 0) {
            const float* xs = x + (size_t)urow * Dd + up * 16;
#pragma unroll
            for (int j = 0; j < 16; ++j) rn[j] = xs[j] - cbrow[j];
        } else {
            const f16* xr = xcat + (size_t)urow * 512 + up * 16;
            f16x8 h0 = *(const f16x8*)xr;
            f16x8 h1 = *(const f16x8*)(xr + 8);
            f16x8 l0 = *(const f16x8*)(xr + 256);
            f16x8 l1 = *(const f16x8*)(xr + 264);
#pragma unroll
            for (int j = 0; j < 8; ++j) {
                rn[j]     = ((float)h0[j] + (float)l0[j]) * 0.5f - cbrow[j];
                rn[8 + j] = ((float)h1[j] + (float)l1[j]) * 0.5f - cbrow[8 + j];
            }
        }
#pragma unroll
        for (int j = 0; j < 16; ++j) lp = fmaf(rn[j], rn[j], lp);

        if (q == Qq - 1) {
            const float* xs = x + (size_t)urow * Dd + up * 16;
            float* oq = outq + (size_t)urow * Dd + up * 16;
#pragma unroll
            for (int j = 0; j < 16; ++j) oq[j] = xs[j] - rn[j];
        } else {
            f16* xr = xcat + (size_t)urow * 512 + up * 16;
#pragma unroll
            for (int c = 0; c < 2; ++c) {
                f16x8 hi, lo;
#pragma unroll
                for (int j = 0; j < 8; ++j) {
                    float v = 2.f * rn[c * 8 + j];
                    f16 h = (f16)v;
                    hi[j] = h; lo[j] = (f16)(v - (float)h);
                }
                *(f16x8*)(xr + c * 8) = hi;
                *(f16x8*)(xr + 256 + c * 8) = lo;
            }
        }
        if (up == 0) idxs[(size_t)q * Nn + urow] = (float)k;

        // block loss partial -> one atomic
#pragma unroll
        for (int off = 32; off >= 1; off >>= 1) lp += __shfl_down(lp, off);
        if (l == 0) lred[w] = lp;
        __syncthreads();
        if (tid == 0) {
            float s = 0.f;
#pragma unroll
            for (int i = 0; i < 8; ++i) s += lred[i];
            atomicAdd(losses + q, s * (1.0f / ((float)Nn * (float)Dd)));
        }
        if (q < Qq - 1) group_sync(myctr, 4 * (++ep));
    }
}

extern "C" void kernel_launch(void* const* d_in, const int* in_sizes, int n_in,
                              void* d_out, int out_size, void* d_ws, size_t ws_size,
                              hipStream_t stream) {
    const float* x   = (const float*)d_in[0];   // [N,D]
    const float* cbs = (const float*)d_in[1];   // [Q,K,D]
    float* out    = (float*)d_out;
    float* idxs   = out + (size_t)Nn * Dd;        // [Q*N]
    float* losses = idxs + (size_t)Qq * Nn;       // [Q]

    f16* xcat    = (f16*)d_ws;                          // [N][512]
    f16* ecat    = xcat + (size_t)Nn * 512;             // [Q*K][512]
    float* norms = (float*)(ecat + (size_t)Qq * Kk * 512);  // [Q*K]
    float2* partial = (float2*)(norms + (size_t)Qq * Kk);   // [4][N]
    unsigned* ctr   = (unsigned*)(partial + (size_t)4 * Nn); // [128]

    hipMemsetAsync(losses, 0, Qq * sizeof(float), stream);
    hipMemsetAsync(ctr, 0, 128 * sizeof(unsigned), stream);
    build_ecat<<<(Qq * Kk) / 8, 256, 0, stream>>>(cbs, ecat, norms);
    rvq_mega<<<512, 512, 0, stream>>>(x, cbs, ecat, norms, xcat, partial,
                                      out, idxs, losses, ctr);
}

// Round 8
// 512.828 us; speedup vs baseline: 2.2217x; 2.2217x over previous
//
#include <hip/hip_runtime.h>

// ResidualVQ: B=8, T=2048, D=256, Q=8, K=1024. N = B*T = 16384.
// Scoring via fp16 split-MFMA: 2x = xh + xl, e = eh + el (fp16 RTNE).
// 2x.e ~= xh.eh + xh.el + xl.eh  (dropped xl.el ~ 2e-6, below fp32 noise).
// One GEMM, reduce length 768, mapped into 512-wide packed buffers:
//   d' in [0,512):   A: ecat col d' (eh|el)    B: xcat col (d' < 256 ? d' : d'-256)
//   d' in [512,768): A: ecat col d'-512 (eh)   B: xcat col d'-256 (xl)
// score = acc - |e|^2  (row-constant |x|^2 dropped; same argmax).
//
// ROUND 8: split kernels (round-6 structure) + 8-phase-style score schedule:
// block = 256 codes x 256 tokens, grid 256 (1 block/CU), 8 waves (2 code-half
// x 4 token-quarter), BK=32, 4-buffer LDS ring (128 KB), 2 phases per K-tile
// {stage half-tile || ds_read frags || setprio(1) 16 MFMA setprio(0) || raw
// s_barrier}, counted vmcnt(4) ONLY at K-tile boundaries (stages stay in
// flight ~2 K-tiles = 8 phases). T2 chunk swizzle cc^=((row>>1)&3) both-sides
// (pre-swizzled global source, linear LDS dest, swizzled ds_read).
//
// d_out (float): [0, N*D) quantized_out; [N*D,+Q*N) indices; [+Q) losses
// d_ws: xcat f16[N][512] | ecat f16[Q*K][512] | norms f32[Q*K] | partial float2[4][N]

typedef _Float16 f16;
typedef f16 f16x8 __attribute__((ext_vector_type(8)));
typedef float f32x4 __attribute__((ext_vector_type(4)));

constexpr int Dd = 256;
constexpr int Kk = 1024;
constexpr int Qq = 8;
constexpr int Nn = 16384;

__device__ inline void gload16(const f16* g, f16* l) {
    __builtin_amdgcn_global_load_lds(
        (const __attribute__((address_space(1))) unsigned int*)(const __attribute__((address_space(1))) f16*)g,
        (__attribute__((address_space(3))) unsigned int*)(__attribute__((address_space(3))) f16*)l,
        16, 0, 0);
}

// ---- build ecat[Q*K][512] = [eh|el] + squared norms, from fp32 codebooks ----
__global__ __launch_bounds__(256) void build_ecat(const float* __restrict__ cb,
                                                  f16* __restrict__ ecat,
                                                  float* __restrict__ norms) {
    int row = blockIdx.x * 8 + (threadIdx.x >> 5);
    int p = threadIdx.x & 31;
    const float* s = cb + (size_t)row * Dd + p * 8;
    f16x8 hi, lo;
    float sq = 0.f;
#pragma unroll
    for (int j = 0; j < 8; ++j) {
        float v = s[j];
        f16 h = (f16)v;
        hi[j] = h; lo[j] = (f16)(v - (float)h);
        sq = fmaf(v, v, sq);
    }
    *(f16x8*)(ecat + (size_t)row * 512 + p * 8) = hi;
    *(f16x8*)(ecat + (size_t)row * 512 + 256 + p * 8) = lo;
#pragma unroll
    for (int off = 16; off >= 1; off >>= 1) sq += __shfl_down(sq, off, 32);
    if (p == 0) norms[row] = sq;
}

// ---- build xcat[N][512] = [xh|xl] of 2*x (layer 0) ----
__global__ __launch_bounds__(256) void build_xcat(const float* __restrict__ src,
                                                  f16* __restrict__ xcat) {
    int row = blockIdx.x * 8 + (threadIdx.x >> 5);
    int p = threadIdx.x & 31;
    const float* s = src + (size_t)row * Dd + p * 8;
    f16x8 hi, lo;
#pragma unroll
    for (int j = 0; j < 8; ++j) {
        float v = 2.f * s[j];
        f16 h = (f16)v;
        hi[j] = h; lo[j] = (f16)(v - (float)h);
    }
    *(f16x8*)(xcat + (size_t)row * 512 + p * 8) = hi;
    *(f16x8*)(xcat + (size_t)row * 512 + 256 + p * 8) = lo;
}

// ---- scoring: block = 256-code slice x 256 tokens, 8 waves, top-1 ----
__global__ __launch_bounds__(512, 2) void score_kernel(
    const f16* __restrict__ xcat,     // [N][512]
    const f16* __restrict__ ecat,     // this layer [K][512]
    const float* __restrict__ norms,  // this layer [K]
    float2* __restrict__ partial)     // [4][N] (val, idx-as-float)
{
    __shared__ f16 sA[4][8192];       // 4 x 16 KB: 256 codes x 32 cols
    __shared__ f16 sB[4][8192];       // 4 x 16 KB: 256 tokens x 32 cols
    __shared__ float smn[256];
    __shared__ float2 smg[2][256];

    const int tid = threadIdx.x;
    const int w = tid >> 6, l = tid & 63;
    const int wr = w >> 2, wc = w & 3;          // wr: code half, wc: token quarter
    const int l16 = l & 15, hi4 = l >> 4;

    // XCD-aligned: 4 slice-blocks of one 256-token tile share (b & 7).
    const int b = blockIdx.x;
    const int slice = (b >> 3) & 3;             // 256-code slice
    const int tokt = ((b >> 5) << 3) | (b & 7); // 64 token tiles
    const int tbase = tokt * 256;
    const int qcb = slice * 256;

    if (tid < 256) smn[tid] = norms[qcb + tid];

    // Staging: thread t -> LDS chunks t and 512+t (linear, gload_lds rule);
    // source col-chunk pre-swizzled: g = (t&3) ^ ((t>>3)&3)  [= (row>>1)&3].
    const int srow = tid >> 2;
    const int g = ((tid & 3) ^ ((tid >> 3) & 3)) * 8;
    const f16* ga0 = ecat + (size_t)(qcb + srow) * 512 + g;
    const f16* ga1 = ga0 + (size_t)128 * 512;
    const f16* gb0 = xcat + (size_t)(tbase + srow) * 512 + g;
    const f16* gb1 = gb0 + (size_t)128 * 512;

    // ds_read offsets with the same involution: cc = hi4 ^ ((row>>1)&3)
    int offA[8], offB[4];
#pragma unroll
    for (int m = 0; m < 8; ++m) {
        int row = wr * 128 + m * 16 + l16;
        offA[m] = row * 32 + ((hi4 ^ ((row >> 1) & 3)) * 8);
    }
#pragma unroll
    for (int n = 0; n < 4; ++n) {
        int row = wc * 64 + n * 16 + l16;
        offB[n] = row * 32 + ((hi4 ^ ((row >> 1) & 3)) * 8);
    }

    f32x4 acc[8][4];
#pragma unroll
    for (int m = 0; m < 8; ++m)
#pragma unroll
        for (int n = 0; n < 4; ++n) acc[m][n] = (f32x4){0.f, 0.f, 0.f, 0.f};

#define STAGE_A(NB, J) do { \
        int d0 = (J) * 32; \
        int aoff = d0 < 512 ? d0 : d0 - 512; \
        gload16(ga0 + aoff, &sA[NB][tid * 8]); \
        gload16(ga1 + aoff, &sA[NB][4096 + tid * 8]); \
    } while (0)
#define STAGE_B(NB, J) do { \
        int d0 = (J) * 32; \
        int boff = d0 < 256 ? d0 : d0 - 256; \
        gload16(gb0 + boff, &sB[NB][tid * 8]); \
        gload16(gb1 + boff, &sB[NB][4096 + tid * 8]); \
    } while (0)

    // prologue: K-tiles 0 and 1 in flight; wait tile 0 (4 newest = tile 1)
    STAGE_A(0, 0); STAGE_B(0, 0);
    STAGE_A(1, 1); STAGE_B(1, 1);
    asm volatile("s_waitcnt vmcnt(4)" ::: "memory");
    __builtin_amdgcn_s_barrier();

#pragma unroll
    for (int j = 0; j < 24; ++j) {
        const int buf = j & 3, nb = (j + 2) & 3;
        // ---- phase 0: stage A of tile j+2; compute n=0,1 ----
        if (j + 2 < 24) STAGE_A(nb, j + 2);
        f16x8 af[8];
#pragma unroll
        for (int m = 0; m < 8; ++m) af[m] = *(const f16x8*)&sA[buf][offA[m]];
        f16x8 b0 = *(const f16x8*)&sB[buf][offB[0]];
        f16x8 b1 = *(const f16x8*)&sB[buf][offB[1]];
        __builtin_amdgcn_s_setprio(1);
#pragma unroll
        for (int m = 0; m < 8; ++m)
            acc[m][0] = __builtin_amdgcn_mfma_f32_16x16x32_f16(af[m], b0, acc[m][0], 0, 0, 0);
#pragma unroll
        for (int m = 0; m < 8; ++m)
            acc[m][1] = __builtin_amdgcn_mfma_f32_16x16x32_f16(af[m], b1, acc[m][1], 0, 0, 0);
        __builtin_amdgcn_s_setprio(0);
        __builtin_amdgcn_s_barrier();
        // ---- phase 1: stage B of tile j+2; compute n=2,3 ----
        if (j + 2 < 24) STAGE_B(nb, j + 2);
        f16x8 b2 = *(const f16x8*)&sB[buf][offB[2]];
        f16x8 b3 = *(const f16x8*)&sB[buf][offB[3]];
        __builtin_amdgcn_s_setprio(1);
#pragma unroll
        for (int m = 0; m < 8; ++m)
            acc[m][2] = __builtin_amdgcn_mfma_f32_16x16x32_f16(af[m], b2, acc[m][2], 0, 0, 0);
#pragma unroll
        for (int m = 0; m < 8; ++m)
            acc[m][3] = __builtin_amdgcn_mfma_f32_16x16x32_f16(af[m], b3, acc[m][3], 0, 0, 0);
        __builtin_amdgcn_s_setprio(0);
        // ---- K-tile boundary: counted drain (next tile landed, one in flight) ----
        if (j < 23) {
            if (j < 22) asm volatile("s_waitcnt vmcnt(4)" ::: "memory");
            else        asm volatile("s_waitcnt vmcnt(0)" ::: "memory");
            __builtin_amdgcn_s_barrier();
        }
    }
#undef STAGE_A
#undef STAGE_B

    // epilogue: score = acc - |e|^2 ; top-1 (ascending code order)
    float bv[4]; int bi[4];
#pragma unroll
    for (int n = 0; n < 4; ++n) { bv[n] = -3.4e38f; bi[n] = 0; }
#pragma unroll
    for (int m = 0; m < 8; ++m) {
#pragma unroll
        for (int r = 0; r < 4; ++r) {
            int cl = wr * 128 + m * 16 + hi4 * 4 + r;   // code local in 256-slice
            float nrm = smn[cl];
            int cg = qcb + cl;
#pragma unroll
            for (int n = 0; n < 4; ++n) {
                float v = acc[m][n][r] - nrm;
                if (v > bv[n]) { bv[n] = v; bi[n] = cg; }
            }
        }
    }
    // merge across the lane>>4 groups (same token, different codes)
#pragma unroll
    for (int off = 16; off <= 32; off <<= 1) {
#pragma unroll
        for (int n = 0; n < 4; ++n) {
            float ov = __shfl_xor(bv[n], off);
            int oi = __shfl_xor(bi[n], off);
            if (ov > bv[n] || (ov == bv[n] && oi < bi[n])) { bv[n] = ov; bi[n] = oi; }
        }
    }
    if (l < 16) {
#pragma unroll
        for (int n = 0; n < 4; ++n)
            smg[wr][wc * 64 + n * 16 + l] = make_float2(bv[n], (float)bi[n]);
    }
    __syncthreads();
    // merge the two code-half wave groups
    if (tid < 256) {
        float2 a = smg[0][tid], c = smg[1][tid];
        float2 r = (c.x > a.x || (c.x == a.x && c.y < a.y)) ? c : a;
        partial[(size_t)slice * Nn + tbase + tid] = r;
    }
}

// ---- update: merge 4 partials, gather e, next xcat (or final resid), loss, idx ----
__global__ __launch_bounds__(256) void update_kernel(
    const float* __restrict__ x,       // original input (used when q==0)
    float* __restrict__ resid_out,     // d_out region (written when last==1)
    const float* __restrict__ cb,      // layer codebook [K][D] fp32
    const float2* __restrict__ partial,
    f16* __restrict__ xcat,            // read (q>0 src) and written (next layer)
    float* __restrict__ idx_out,
    float* __restrict__ loss_out,
    int q, int last)
{
    __shared__ float lsum[8];
    const int tid = threadIdx.x;
    const int row = blockIdx.x * 8 + (tid >> 5);
    const int p = tid & 31;

    float2 bsel = partial[row];
#pragma unroll
    for (int qq = 1; qq < 4; ++qq) {
        float2 c = partial[(size_t)qq * Nn + row];
        if (c.x > bsel.x || (c.x == bsel.x && c.y < bsel.y)) bsel = c;
    }
    const int k = (int)bsel.y;

    const float* e = cb + (size_t)k * Dd + p * 8;
    float rn[8];
    float lp = 0.f;
    if (q == 0) {
        const float* r = x + (size_t)row * Dd + p * 8;
#pragma unroll
        for (int j = 0; j < 8; ++j) rn[j] = r[j] - e[j];
    } else {
        f16x8 xh = *(const f16x8*)(xcat + (size_t)row * 512 + p * 8);
        f16x8 xl = *(const f16x8*)(xcat + (size_t)row * 512 + 256 + p * 8);
#pragma unroll
        for (int j = 0; j < 8; ++j) {
            float r = ((float)xh[j] + (float)xl[j]) * 0.5f;
            rn[j] = r - e[j];
        }
    }
#pragma unroll
    for (int j = 0; j < 8; ++j) lp = fmaf(rn[j], rn[j], lp);

    if (last) {
        float* ro = resid_out + (size_t)row * Dd + p * 8;
#pragma unroll
        for (int j = 0; j < 8; ++j) ro[j] = rn[j];
    } else {
        f16x8 hi2, lo2;
#pragma unroll
        for (int j = 0; j < 8; ++j) {
            float v = 2.f * rn[j];
            f16 h = (f16)v;
            hi2[j] = h; lo2[j] = (f16)(v - (float)h);
        }
        *(f16x8*)(xcat + (size_t)row * 512 + p * 8) = hi2;
        *(f16x8*)(xcat + (size_t)row * 512 + 256 + p * 8) = lo2;
    }
    if (p == 0) idx_out[row] = (float)k;

#pragma unroll
    for (int off = 16; off >= 1; off >>= 1) lp += __shfl_down(lp, off, 32);
    if (p == 0) lsum[tid >> 5] = lp;
    __syncthreads();
    if (tid == 0) {
        float s = 0.f;
#pragma unroll
        for (int i = 0; i < 8; ++i) s += lsum[i];
        atomicAdd(loss_out, s * (1.0f / ((float)Nn * (float)Dd)));
    }
}

// ---- finalize: quantized_out = x - final_residual (in place in d_out) ----
__global__ __launch_bounds__(256) void finalize_kernel(const float* __restrict__ x,
                                                       float* __restrict__ out) {
    const float4* xg = (const float4*)x;
    float4* og = (float4*)out;
    size_t n4 = (size_t)Nn * Dd / 4;
    for (size_t i = (size_t)blockIdx.x * 256 + threadIdx.x; i < n4;
         i += (size_t)gridDim.x * 256) {
        float4 a = xg[i], b2 = og[i];
        float4 o;
        o.x = a.x - b2.x; o.y = a.y - b2.y; o.z = a.z - b2.z; o.w = a.w - b2.w;
        og[i] = o;
    }
}

extern "C" void kernel_launch(void* const* d_in, const int* in_sizes, int n_in,
                              void* d_out, int out_size, void* d_ws, size_t ws_size,
                              hipStream_t stream) {
    const float* x   = (const float*)d_in[0];   // [N,D]
    const float* cbs = (const float*)d_in[1];   // [Q,K,D]
    float* out    = (float*)d_out;
    float* resid  = out;                          // final residual lives here
    float* idxs   = out + (size_t)Nn * Dd;        // [Q*N]
    float* losses = idxs + (size_t)Qq * Nn;       // [Q]

    f16* xcat    = (f16*)d_ws;                          // [N][512]
    f16* ecat    = xcat + (size_t)Nn * 512;             // [Q*K][512]
    float* norms = (float*)(ecat + (size_t)Qq * Kk * 512);  // [Q*K]
    float2* partial = (float2*)(norms + (size_t)Qq * Kk);   // [4][N]

    hipMemsetAsync(losses, 0, Qq * sizeof(float), stream);
    build_ecat<<<(Qq * Kk) / 8, 256, 0, stream>>>(cbs, ecat, norms);
    build_xcat<<<Nn / 8, 256, 0, stream>>>(x, xcat);

    for (int q = 0; q < Qq; ++q) {
        score_kernel<<<256, 512, 0, stream>>>(
            xcat, ecat + (size_t)q * Kk * 512, norms + (size_t)q * Kk, partial);
        update_kernel<<<Nn / 8, 256, 0, stream>>>(
            x, resid, cbs + (size_t)q * Kk * Dd, partial, xcat,
            idxs + (size_t)q * Nn, losses + q, q, q == Qq - 1 ? 1 : 0);
    }
    finalize_kernel<<<1024, 256, 0, stream>>>(x, out);
}

// Round 10
// 388.531 us; speedup vs baseline: 2.9324x; 1.3199x over previous
//
#include <hip/hip_runtime.h>

// ResidualVQ: B=8, T=2048, D=256, Q=8, K=1024. N = B*T = 16384.
// Scoring via fp16 split-MFMA: 2x = xh + xl, e = eh + el (fp16 RTNE).
// 2x.e ~= xh.eh + xh.el + xl.eh  (dropped xl.el ~ 2e-6, below fp32 noise).
// One GEMM, reduce length 768, mapped into 512-wide packed buffers:
//   d' in [0,512):   A: ecat col d' (eh|el)    B: xcat col (d' < 256 ? d' : d'-256)
//   d' in [512,768): A: ecat col d'-512 (eh)   B: xcat col d'-256 (xl)
// score = acc - |e|^2  (row-constant |x|^2 dropped; same argmax).
//
// ROUND 10 = round 9 + the race fix: xcat is PARITY DOUBLE-BUFFERED.
// Round 9's fused update did an in-place RMW on xcat while 4 slice-blocks
// redundantly updated the same rows -> peer could overwrite before read.
// Now update reads xb[(q-1)&1] (written last launch, stable) and writes
// xb[q&1] (redundant writes byte-identical; GEMM reads own-block stores
// after __syncthreads vmcnt drain -- pattern validated by round 7).
//
// d_out (float): [0, N*D) quantized_out; [N*D,+Q*N) indices; [+Q) losses
// d_ws: xb f16[2][N][512] | ecat f16[Q*K][512] | norms f32[Q*K]
//       | partial float2[2][4][N] (layer-parity double buffer)

typedef _Float16 f16;
typedef f16 f16x8 __attribute__((ext_vector_type(8)));
typedef float f32x4 __attribute__((ext_vector_type(4)));

constexpr int Dd = 256;
constexpr int Kk = 1024;
constexpr int Qq = 8;
constexpr int Nn = 16384;

__device__ inline void gload16(const f16* g, f16* l) {
    __builtin_amdgcn_global_load_lds(
        (const __attribute__((address_space(1))) unsigned int*)(const __attribute__((address_space(1))) f16*)g,
        (__attribute__((address_space(3))) unsigned int*)(__attribute__((address_space(3))) f16*)l,
        16, 0, 0);
}

// ---- build ecat[Q*K][512] = [eh|el] + squared norms, from fp32 codebooks ----
__global__ __launch_bounds__(256) void build_ecat(const float* __restrict__ cb,
                                                  f16* __restrict__ ecat,
                                                  float* __restrict__ norms) {
    int row = blockIdx.x * 8 + (threadIdx.x >> 5);
    int p = threadIdx.x & 31;
    const float* s = cb + (size_t)row * Dd + p * 8;
    f16x8 hi, lo;
    float sq = 0.f;
#pragma unroll
    for (int j = 0; j < 8; ++j) {
        float v = s[j];
        f16 h = (f16)v;
        hi[j] = h; lo[j] = (f16)(v - (float)h);
        sq = fmaf(v, v, sq);
    }
    *(f16x8*)(ecat + (size_t)row * 512 + p * 8) = hi;
    *(f16x8*)(ecat + (size_t)row * 512 + 256 + p * 8) = lo;
#pragma unroll
    for (int off = 16; off >= 1; off >>= 1) sq += __shfl_down(sq, off, 32);
    if (p == 0) norms[row] = sq;
}

// ---- score layer q (+fused update of layer q-1) ----
// block = 256-code slice x 256 tokens, 8 waves (2 code-half x 4 token-quarter)
__global__ __launch_bounds__(512, 2) void score_kernel(
    const float* __restrict__ x,        // [N][256]
    const float* __restrict__ cb_prev,  // layer q-1 codebook [K][256] (q>0)
    const f16* __restrict__ ecat,       // this layer [K][512]
    const float* __restrict__ norms,    // this layer [K]
    const f16* __restrict__ xold,       // xb[(q-1)&1] (q>0 src; stable)
    f16* __restrict__ xnew,             // xb[q&1] (written; GEMM input)
    const float2* __restrict__ pin,     // partial layer q-1
    float2* __restrict__ pout,          // partial layer q
    float* __restrict__ idx_prev,       // [N] (q>0, slice0)
    float* __restrict__ loss_prev,      // scalar (q>0, slice0)
    int q)
{
    __shared__ f16 sA[4][8192];       // 4 x 16 KB: 256 codes x 32 cols
    __shared__ f16 sB[4][8192];       // 4 x 16 KB: 256 tokens x 32 cols
    __shared__ float smn[256];
    __shared__ float2 smg[2][256];
    __shared__ float lred[8];

    const int tid = threadIdx.x;
    const int w = tid >> 6, l = tid & 63;
    const int wr = w >> 2, wc = w & 3;          // wr: code half, wc: token quarter
    const int l16 = l & 15, hi4 = l >> 4;

    // XCD-aligned: 4 slice-blocks of one 256-token tile share (b & 7).
    const int b = blockIdx.x;
    const int slice = (b >> 3) & 3;             // 256-code slice
    const int tokt = ((b >> 5) << 3) | (b & 7); // 64 token tiles
    const int tbase = tokt * 256;
    const int qcb = slice * 256;

    // ================= fused update phase (layer q-1 -> xnew tile) ====
    {
        const int up = tid & 15;
        const int d0 = up * 16;
        float lp = 0.f;
#pragma unroll 1
        for (int pass = 0; pass < 8; ++pass) {
            const int row = tbase + pass * 32 + (tid >> 4);
            f16* xw = xnew + (size_t)row * 512;
            if (q == 0) {
                const float* xs = x + (size_t)row * Dd + d0;
#pragma unroll
                for (int c = 0; c < 2; ++c) {
                    f16x8 hi, lo;
#pragma unroll
                    for (int j = 0; j < 8; ++j) {
                        float v = 2.f * xs[c * 8 + j];
                        f16 h = (f16)v;
                        hi[j] = h; lo[j] = (f16)(v - (float)h);
                    }
                    *(f16x8*)(xw + d0 + c * 8) = hi;
                    *(f16x8*)(xw + 256 + d0 + c * 8) = lo;
                }
            } else {
                float2 bsel = pin[row];
#pragma unroll
                for (int s2 = 1; s2 < 4; ++s2) {
                    float2 c2 = pin[(size_t)s2 * Nn + row];
                    if (c2.x > bsel.x || (c2.x == bsel.x && c2.y < bsel.y)) bsel = c2;
                }
                const int k = (int)bsel.y;
                const float* e = cb_prev + (size_t)k * Dd + d0;
                const f16* xr = xold + (size_t)row * 512;
                f16x8 h0 = *(const f16x8*)(xr + d0);
                f16x8 h1 = *(const f16x8*)(xr + d0 + 8);
                f16x8 l0 = *(const f16x8*)(xr + 256 + d0);
                f16x8 l1 = *(const f16x8*)(xr + 256 + d0 + 8);
                float rn[16];
#pragma unroll
                for (int j = 0; j < 8; ++j) {
                    rn[j]     = ((float)h0[j] + (float)l0[j]) * 0.5f - e[j];
                    rn[8 + j] = ((float)h1[j] + (float)l1[j]) * 0.5f - e[8 + j];
                }
#pragma unroll
                for (int j = 0; j < 16; ++j) lp = fmaf(rn[j], rn[j], lp);
#pragma unroll
                for (int c = 0; c < 2; ++c) {
                    f16x8 hi, lo;
#pragma unroll
                    for (int j = 0; j < 8; ++j) {
                        float v = 2.f * rn[c * 8 + j];
                        f16 h = (f16)v;
                        hi[j] = h; lo[j] = (f16)(v - (float)h);
                    }
                    *(f16x8*)(xw + d0 + c * 8) = hi;
                    *(f16x8*)(xw + 256 + d0 + c * 8) = lo;
                }
                if (slice == 0 && up == 0) idx_prev[row] = (float)k;
            }
        }
        if (q > 0 && slice == 0) {
#pragma unroll
            for (int off = 32; off >= 1; off >>= 1) lp += __shfl_down(lp, off);
            if (l == 0) lred[w] = lp;
        }
    }
    if (tid < 256) smn[tid] = norms[qcb + tid];
    __syncthreads();   // drains vmcnt(0): xnew stores visible to gload_lds
    if (q > 0 && slice == 0 && tid == 0) {
        float s = 0.f;
#pragma unroll
        for (int i = 0; i < 8; ++i) s += lred[i];
        atomicAdd(loss_prev, s * (1.0f / ((float)Nn * (float)Dd)));
    }

    // ================= GEMM phase =================
    // Staging: thread t -> LDS chunks t and 512+t (linear, gload_lds rule);
    // source col-chunk pre-swizzled: g = (t&3) ^ ((t>>3)&3)  [= (row>>1)&3].
    const int srow = tid >> 2;
    const int g = ((tid & 3) ^ ((tid >> 3) & 3)) * 8;
    const f16* ga0 = ecat + (size_t)(qcb + srow) * 512 + g;
    const f16* ga1 = ga0 + (size_t)128 * 512;
    const f16* gb0 = xnew + (size_t)(tbase + srow) * 512 + g;
    const f16* gb1 = gb0 + (size_t)128 * 512;

    // ds_read offsets with the same involution: cc = hi4 ^ ((row>>1)&3)
    int offA[8], offB[4];
#pragma unroll
    for (int m = 0; m < 8; ++m) {
        int row = wr * 128 + m * 16 + l16;
        offA[m] = row * 32 + ((hi4 ^ ((row >> 1) & 3)) * 8);
    }
#pragma unroll
    for (int n = 0; n < 4; ++n) {
        int row = wc * 64 + n * 16 + l16;
        offB[n] = row * 32 + ((hi4 ^ ((row >> 1) & 3)) * 8);
    }

    f32x4 acc[8][4];
#pragma unroll
    for (int m = 0; m < 8; ++m)
#pragma unroll
        for (int n = 0; n < 4; ++n) acc[m][n] = (f32x4){0.f, 0.f, 0.f, 0.f};

#define STAGE(NB, J) do { \
        int d0s = (J) * 32; \
        int aoff = d0s < 512 ? d0s : d0s - 512; \
        int boff = d0s < 256 ? d0s : d0s - 256; \
        gload16(ga0 + aoff, &sA[NB][tid * 8]); \
        gload16(ga1 + aoff, &sA[NB][4096 + tid * 8]); \
        gload16(gb0 + boff, &sB[NB][tid * 8]); \
        gload16(gb1 + boff, &sB[NB][4096 + tid * 8]); \
    } while (0)

    // prologue: K-tiles 0,1 in flight; wait tile 0 (4 newest = tile 1)
    STAGE(0, 0);
    STAGE(1, 1);
    asm volatile("s_waitcnt vmcnt(4)\n\ts_barrier" ::: "memory");

#pragma unroll
    for (int j = 0; j < 24; ++j) {
        const int buf = j & 3;
        if (j + 2 < 24) STAGE((j + 2) & 3, j + 2);
        f16x8 bf[4], af[8];
#pragma unroll
        for (int n = 0; n < 4; ++n) bf[n] = *(const f16x8*)&sB[buf][offB[n]];
#pragma unroll
        for (int m = 0; m < 8; ++m) af[m] = *(const f16x8*)&sA[buf][offA[m]];
        __builtin_amdgcn_s_setprio(1);
#pragma unroll
        for (int m = 0; m < 8; ++m)
#pragma unroll
            for (int n = 0; n < 4; ++n)
                acc[m][n] = __builtin_amdgcn_mfma_f32_16x16x32_f16(af[m], bf[n], acc[m][n], 0, 0, 0);
        __builtin_amdgcn_s_setprio(0);
        if (j < 23) {
            if (j < 22) asm volatile("s_waitcnt vmcnt(4)\n\ts_barrier" ::: "memory");
            else        asm volatile("s_waitcnt vmcnt(0)\n\ts_barrier" ::: "memory");
        }
    }
#undef STAGE

    // epilogue: score = acc - |e|^2 ; top-1 (ascending code order)
    float bv[4]; int bi[4];
#pragma unroll
    for (int n = 0; n < 4; ++n) { bv[n] = -3.4e38f; bi[n] = 0; }
#pragma unroll
    for (int m = 0; m < 8; ++m) {
#pragma unroll
        for (int r = 0; r < 4; ++r) {
            int cl = wr * 128 + m * 16 + hi4 * 4 + r;   // code local in 256-slice
            float nrm = smn[cl];
            int cg = qcb + cl;
#pragma unroll
            for (int n = 0; n < 4; ++n) {
                float v = acc[m][n][r] - nrm;
                if (v > bv[n]) { bv[n] = v; bi[n] = cg; }
            }
        }
    }
    // merge across the lane>>4 groups (same token, different codes)
#pragma unroll
    for (int off = 16; off <= 32; off <<= 1) {
#pragma unroll
        for (int n = 0; n < 4; ++n) {
            float ov = __shfl_xor(bv[n], off);
            int oi = __shfl_xor(bi[n], off);
            if (ov > bv[n] || (ov == bv[n] && oi < bi[n])) { bv[n] = ov; bi[n] = oi; }
        }
    }
    if (l < 16) {
#pragma unroll
        for (int n = 0; n < 4; ++n)
            smg[wr][wc * 64 + n * 16 + l] = make_float2(bv[n], (float)bi[n]);
    }
    __syncthreads();
    // merge the two code-half wave groups
    if (tid < 256) {
        float2 a = smg[0][tid], c = smg[1][tid];
        float2 r = (c.x > a.x || (c.x == a.x && c.y < a.y)) ? c : a;
        pout[(size_t)slice * Nn + tbase + tid] = r;
    }
}

// ---- final: merge partial(7), idx7, loss7, out = x - r8 ----
__global__ __launch_bounds__(256) void final_kernel(
    const float* __restrict__ x,
    const float* __restrict__ cb7,      // layer 7 codebook
    const f16* __restrict__ xcat,       // xb[1]: holds split(2*r7)
    const float2* __restrict__ pin,     // partial layer 7
    float* __restrict__ out,
    float* __restrict__ idx7,
    float* __restrict__ loss7)
{
    __shared__ float lsum[4];
    const int tid = threadIdx.x;
    const int row = blockIdx.x * 16 + (tid >> 4);
    const int d0 = (tid & 15) * 16;

    float2 bsel = pin[row];
#pragma unroll
    for (int s2 = 1; s2 < 4; ++s2) {
        float2 c2 = pin[(size_t)s2 * Nn + row];
        if (c2.x > bsel.x || (c2.x == bsel.x && c2.y < bsel.y)) bsel = c2;
    }
    const int k = (int)bsel.y;
    const float* e = cb7 + (size_t)k * Dd + d0;
    const f16* xr = xcat + (size_t)row * 512;
    const float* xs = x + (size_t)row * Dd + d0;
    float* os = out + (size_t)row * Dd + d0;

    f16x8 h0 = *(const f16x8*)(xr + d0);
    f16x8 h1 = *(const f16x8*)(xr + d0 + 8);
    f16x8 l0 = *(const f16x8*)(xr + 256 + d0);
    f16x8 l1 = *(const f16x8*)(xr + 256 + d0 + 8);
    float lp = 0.f;
#pragma unroll
    for (int j = 0; j < 8; ++j) {
        float r7a = ((float)h0[j] + (float)l0[j]) * 0.5f;
        float r7b = ((float)h1[j] + (float)l1[j]) * 0.5f;
        float r8a = r7a - e[j];
        float r8b = r7b - e[8 + j];
        os[j]     = xs[j] - r8a;
        os[8 + j] = xs[8 + j] - r8b;
        lp = fmaf(r8a, r8a, lp);
        lp = fmaf(r8b, r8b, lp);
    }
    if ((tid & 15) == 0) idx7[row] = (float)k;

#pragma unroll
    for (int off = 32; off >= 1; off >>= 1) lp += __shfl_down(lp, off);
    if ((tid & 63) == 0) lsum[tid >> 6] = lp;
    __syncthreads();
    if (tid == 0) {
        float s = lsum[0] + lsum[1] + lsum[2] + lsum[3];
        atomicAdd(loss7, s * (1.0f / ((float)Nn * (float)Dd)));
    }
}

extern "C" void kernel_launch(void* const* d_in, const int* in_sizes, int n_in,
                              void* d_out, int out_size, void* d_ws, size_t ws_size,
                              hipStream_t stream) {
    const float* x   = (const float*)d_in[0];   // [N,D]
    const float* cbs = (const float*)d_in[1];   // [Q,K,D]
    float* out    = (float*)d_out;
    float* idxs   = out + (size_t)Nn * Dd;        // [Q*N]
    float* losses = idxs + (size_t)Qq * Nn;       // [Q]

    f16* xb0     = (f16*)d_ws;                          // [N][512]
    f16* xb1     = xb0 + (size_t)Nn * 512;              // [N][512]
    f16* ecat    = xb1 + (size_t)Nn * 512;              // [Q*K][512]
    float* norms = (float*)(ecat + (size_t)Qq * Kk * 512);  // [Q*K]
    float2* part0 = (float2*)(norms + (size_t)Qq * Kk);     // [4][N]
    float2* part1 = part0 + (size_t)4 * Nn;                 // [4][N]

    hipMemsetAsync(losses, 0, Qq * sizeof(float), stream);
    build_ecat<<<(Qq * Kk) / 8, 256, 0, stream>>>(cbs, ecat, norms);

    for (int q = 0; q < Qq; ++q) {
        float2* pin  = (q & 1) ? part1 : part0;   // layer q-1 partials
        float2* pout = (q & 1) ? part0 : part1;   // layer q partials
        const f16* xold = (q & 1) ? xb0 : xb1;    // xb[(q-1)&1]
        f16* xnew       = (q & 1) ? xb1 : xb0;    // xb[q&1]
        score_kernel<<<256, 512, 0, stream>>>(
            x,
            q > 0 ? cbs + (size_t)(q - 1) * Kk * Dd : cbs,
            ecat + (size_t)q * Kk * 512, norms + (size_t)q * Kk,
            xold, xnew, pin, pout,
            q > 0 ? idxs + (size_t)(q - 1) * Nn : idxs,
            q > 0 ? losses + (q - 1) : losses,
            q);
    }
    // layer 7 partials: q=7 odd -> pout = part0; r7 split lives in xb[1]
    final_kernel<<<Nn / 16, 256, 0, stream>>>(
        x, cbs + (size_t)7 * Kk * Dd, xb1, part0, out,
        idxs + (size_t)7 * Nn, losses + 7);
}